// Round 7
// baseline (492.369 us; speedup 1.0000x reference)
//
#include <hip/hip_runtime.h>

typedef unsigned short u16;
typedef unsigned int u32;
typedef __bf16 bf16x8 __attribute__((ext_vector_type(8)));
typedef float f32x4 __attribute__((ext_vector_type(4)));
typedef u16 u16x8 __attribute__((ext_vector_type(8)));
typedef u16 u16x4 __attribute__((ext_vector_type(4)));

#define DEV static __device__ __forceinline__

// B=2, T=2048, C=1024, H=16, D=64, DEPTH=3
#define TT 2048
#define CC 1024
#define HH 16
#define DD 64

DEV u16 f2bf(float f) {
    u32 u = __float_as_uint(f);
    u += 0x7fffu + ((u >> 16) & 1u);
    return (u16)(u >> 16);
}

DEV void gload_lds16(const void* g, void* l) {
    __builtin_amdgcn_global_load_lds(
        (const __attribute__((address_space(1))) void*)g,
        (__attribute__((address_space(3))) void*)l,
        16, 0, 0);
}

// ---------------- converts ----------------
__global__ __launch_bounds__(256) void cvt_x(const float* __restrict__ x,
                                             u16* __restrict__ xb, int n4) {
    int i = blockIdx.x * 256 + threadIdx.x;
    if (i < n4) {
        float4 v = ((const float4*)x)[i];
        u16 o0 = f2bf(v.x), o1 = f2bf(v.y), o2 = f2bf(v.z), o3 = f2bf(v.w);
        u32 lo = (u32)o0 | ((u32)o1 << 16);
        u32 hi = (u32)o2 | ((u32)o3 << 16);
        ((u32*)xb)[i * 2]     = lo;
        ((u32*)xb)[i * 2 + 1] = hi;
    }
}

// W [K][N] fp32 -> Wt [N][K] bf16
__global__ __launch_bounds__(256) void cvt_w_t(const float* __restrict__ W,
                                               u16* __restrict__ Wt, int K, int N) {
    __shared__ float tile[32][33];
    int n0 = blockIdx.x * 32, k0 = blockIdx.y * 32;
    int tx = threadIdx.x & 31, ty = threadIdx.x >> 5;  // 32 x 8
#pragma unroll
    for (int i = 0; i < 4; i++)
        tile[ty + i * 8][tx] = W[(size_t)(k0 + ty + i * 8) * N + n0 + tx];
    __syncthreads();
#pragma unroll
    for (int i = 0; i < 4; i++) {
        int rr = ty + i * 8;
        Wt[(size_t)(n0 + rr) * K + k0 + tx] = f2bf(tile[tx][rr]);
    }
}

// ---------------- GEMM: C[M,N] = A[M,K](bf16) * Bt[N,K]^T(bf16) + bias ----------------
// 128x128 tile, BK=32, 4 waves. T3-minimum 2-phase: double-buffered LDS,
// stage(t+1) issued BEFORE compute(t), single vmcnt(0)+barrier per K-step.
template <int OUTF>
__global__ __launch_bounds__(256) void gemm_bf16(const u16* __restrict__ A,
                                                 const u16* __restrict__ Bt,
                                                 const float* __restrict__ bias,
                                                 void* __restrict__ Cout,
                                                 int K, int ldc) {
    __shared__ __align__(16) u16 As[8192];  // 2 x [128][32]
    __shared__ __align__(16) u16 Bs[8192];

    const int tid = threadIdx.x;
    const int w = tid >> 6, l = tid & 63;
    const int wr = w >> 1, wc = w & 1;
    const int c = l & 15, g = l >> 4;
    const int rowB = blockIdx.y * 128;
    const int colB = blockIdx.x * 128;
    const int sr = l >> 2;          // staging row-in-quarter
    const int sk = (l & 3) * 8;     // staging k elem offset

    auto stage = [&](int t, int bb) {
#pragma unroll
        for (int i = 0; i < 2; i++) {
            int r = i * 64 + w * 16 + sr;
            gload_lds16(A + (size_t)(rowB + r) * K + t * 32 + sk, &As[bb * 4096 + i * 2048 + w * 512]);
            gload_lds16(Bt + (size_t)(colB + r) * K + t * 32 + sk, &Bs[bb * 4096 + i * 2048 + w * 512]);
        }
    };

    const f32x4 fz = {0.f, 0.f, 0.f, 0.f};
    f32x4 acc[4][4];
#pragma unroll
    for (int m = 0; m < 4; m++)
#pragma unroll
        for (int n = 0; n < 4; n++) acc[m][n] = fz;

    const int NT = K >> 5;
    stage(0, 0);
    asm volatile("s_waitcnt vmcnt(0)" ::: "memory");
    __syncthreads();

    int cur = 0;
    for (int t = 0; t < NT; t++) {
        if (t + 1 < NT) stage(t + 1, cur ^ 1);   // loads fly during compute
        const int kb = cur * 4096;
        bf16x8 af[4], bfr[4];
#pragma unroll
        for (int m = 0; m < 4; m++)
            af[m] = *(const bf16x8*)&As[kb + (wr * 64 + m * 16 + c) * 32 + g * 8];
#pragma unroll
        for (int n = 0; n < 4; n++)
            bfr[n] = *(const bf16x8*)&Bs[kb + (wc * 64 + n * 16 + c) * 32 + g * 8];
#pragma unroll
        for (int m = 0; m < 4; m++)
#pragma unroll
            for (int n = 0; n < 4; n++)
                acc[m][n] = __builtin_amdgcn_mfma_f32_16x16x32_bf16(af[m], bfr[n], acc[m][n], 0, 0, 0);
        asm volatile("s_waitcnt vmcnt(0)" ::: "memory");
        __syncthreads();  // next tile landed AND everyone done reading buf cur
        cur ^= 1;
    }

    const int orow = rowB + wr * 64;
    const int ocol = colB + wc * 64;
#pragma unroll
    for (int m = 0; m < 4; m++)
#pragma unroll
        for (int n = 0; n < 4; n++) {
            int col = ocol + n * 16 + c;
            float bv = bias[col];
#pragma unroll
            for (int j = 0; j < 4; j++) {
                int row = orow + m * 16 + g * 4 + j;
                float v = acc[m][n][j] + bv;
                if (OUTF)
                    ((float*)Cout)[(size_t)row * ldc + col] = v;
                else
                    ((u16*)Cout)[(size_t)row * ldc + col] = f2bf(v);
            }
        }
}

// ---------------- flash causal attention, one depth ----------------
// Swapped-operand scheme: S = mfma(K, Q) -> S[kv][q=c] lane-local per q-row;
// exp2-domain online softmax (scale folded: SCL = 0.125*log2e), defer-max THR=8,
// P packed via v_cvt_pk_bf16_f32; PV = mfma(V^T, P) -> O^T[d][q=c].
// Pair-balanced: block handles q-tiles (qp, 31-qp) sharing staged K/V tiles.
template <int NQ>
DEV void tile_step(const u16* __restrict__ Kb, const u16* __restrict__ Vb,
                   u16* __restrict__ Psw, const bf16x8 (*qa)[2], f32x4 (*O)[4],
                   float* mX, float* lX, const int* thr, const bool* nm,
                   int c, int g) {
    const f32x4 fz = {0.f, 0.f, 0.f, 0.f};
    const int swz = (c & 7) << 3;
    const float SCL = 0.18033688011112042f;  // 0.125 * log2(e)
    f32x4 s[NQ][4];
#pragma unroll
    for (int q = 0; q < NQ; q++)
#pragma unroll
        for (int m = 0; m < 4; m++) s[q][m] = fz;
    // S = K Q^T  (C layout: row=kv, col=q=c)
    __builtin_amdgcn_s_setprio(1);
#pragma unroll
    for (int ds = 0; ds < 2; ds++)
#pragma unroll
        for (int m = 0; m < 4; m++) {
            bf16x8 kb = *(const bf16x8*)&Kb[(m * 16 + c) * 64 + ((ds * 32 + g * 8) ^ swz)];
#pragma unroll
            for (int q = 0; q < NQ; q++)
                s[q][m] = __builtin_amdgcn_mfma_f32_16x16x32_bf16(kb, qa[q][ds], s[q][m], 0, 0, 0);
        }
    __builtin_amdgcn_s_setprio(0);
#pragma unroll
    for (int q = 0; q < NQ; q++) {
        float m0 = -1e30f;
        if (nm[q]) {
#pragma unroll
            for (int m = 0; m < 4; m++)
#pragma unroll
                for (int j = 0; j < 4; j++) {
                    int kvr = m * 16 + g * 4 + j;
                    float v = (kvr <= thr[q]) ? s[q][m][j] * SCL : -1e30f;
                    s[q][m][j] = v;
                    m0 = fmaxf(m0, v);
                }
        } else {
#pragma unroll
            for (int m = 0; m < 4; m++)
#pragma unroll
                for (int j = 0; j < 4; j++) {
                    float v = s[q][m][j] * SCL;
                    s[q][m][j] = v;
                    m0 = fmaxf(m0, v);
                }
        }
        m0 = fmaxf(m0, __shfl_xor(m0, 16, 64));
        m0 = fmaxf(m0, __shfl_xor(m0, 32, 64));
        // defer-max: bound vs KEPT max -> per-tile P <= 2^8, no drift
        const bool defer = __all(m0 <= mX[q] + 8.f) != 0;
        const float mn = defer ? mX[q] : fmaxf(mX[q], m0);
        float rsum = 0.f;
#pragma unroll
        for (int m = 0; m < 4; m++)
#pragma unroll
            for (int j = 0; j < 4; j++) {
                float p = exp2f(s[q][m][j] - mn);
                s[q][m][j] = p;
                rsum += p;
            }
        rsum += __shfl_xor(rsum, 16, 64);
        rsum += __shfl_xor(rsum, 32, 64);
        if (defer) {
            lX[q] += rsum;
        } else {
            float esc = exp2f(mX[q] - mn);
            mX[q] = mn;
            lX[q] = lX[q] * esc + rsum;
#pragma unroll
            for (int nd = 0; nd < 4; nd++)
#pragma unroll
                for (int j = 0; j < 4; j++) O[q][nd][j] *= esc;
        }
        // P write: Ps[q=c][kv], packed pairs via cvt_pk (8 x ds_write_b32)
#pragma unroll
        for (int m = 0; m < 4; m++)
#pragma unroll
            for (int jj = 0; jj < 2; jj++) {
                u32 pw;
                asm("v_cvt_pk_bf16_f32 %0, %1, %2"
                    : "=v"(pw) : "v"(s[q][m][jj * 2]), "v"(s[q][m][jj * 2 + 1]));
                int kvi = (m * 16 + g * 4 + jj * 2) ^ swz;
                *(u32*)&Psw[q * 1024 + c * 64 + kvi] = pw;
            }
    }
    asm volatile("s_waitcnt lgkmcnt(0)" ::: "memory");
    __builtin_amdgcn_sched_barrier(0);
    // O += V^T P^T  (C layout: row=d, col=q=c)
    __builtin_amdgcn_s_setprio(1);
#pragma unroll
    for (int ks = 0; ks < 2; ks++) {
        bf16x8 pa[NQ];
#pragma unroll
        for (int q = 0; q < NQ; q++)
            pa[q] = *(const bf16x8*)&Psw[q * 1024 + c * 64 + ((ks * 32 + g * 8) ^ swz)];
#pragma unroll
        for (int nd = 0; nd < 4; nd++) {
            bf16x8 vb = *(const bf16x8*)&Vb[(nd * 16 + c) * 64 + ((ks * 32 + g * 8) ^ swz)];
#pragma unroll
            for (int q = 0; q < NQ; q++)
                O[q][nd] = __builtin_amdgcn_mfma_f32_16x16x32_bf16(vb, pa[q], O[q][nd], 0, 0, 0);
        }
    }
    __builtin_amdgcn_s_setprio(0);
}

__global__ __launch_bounds__(256) void attn_kernel(const u16* __restrict__ QKV,  // [B*T][3C]
                                                   const float* __restrict__ gates,
                                                   float* __restrict__ attF,  // [B*T][C] fp32 state (= d_out)
                                                   u16* __restrict__ attB,    // [B*T][C] bf16 copy
                                                   int depth) {
    __shared__ __align__(16) u16 Ks[8192];  // 2 x 8KB
    __shared__ __align__(16) u16 Vs[8192];  // 2 x 8KB
    __shared__ __align__(16) u16 Ps[8192];  // 4 waves x 2 qsets x 2KB

    const int tid = threadIdx.x;
    const int w = tid >> 6, l = tid & 63;
    const int c = l & 15, g = l >> 4;

    // XCD-aware bijective remap: 512 blocks, each XCD owns 4 bh values
    const int f = blockIdx.y * 16 + blockIdx.x;
    const int xcd = f & 7;
    const int idx = f >> 3;                 // 0..63
    const int bh = xcd + 8 * (idx & 3);     // 0..31
    const int qp = idx >> 2;                // pair 0..15
    const int b = bh >> 4, h = bh & 15;
    const int qtB = 31 - qp;                // qset0 (always active)
    const int qtA = qp;                     // qset1 (active t <= qtA)
    const size_t rowbase = (size_t)b * TT;
    const int qrow0[2] = {qtB * 64 + w * 16, qtA * 64 + w * 16};
    const f32x4 fz = {0.f, 0.f, 0.f, 0.f};

    // staging constants
    const int krow = l >> 3;
    const int kcolb = (((l & 7) ^ krow) << 4);

    // Q fragments (B-operand layout): lane holds Q[q=qrow0+c][k=ds*32+g*8..]
    bf16x8 qa[2][2];
#pragma unroll
    for (int q = 0; q < 2; q++)
#pragma unroll
        for (int ds = 0; ds < 2; ds++)
            qa[q][ds] = *(const bf16x8*)&QKV[(rowbase + qrow0[q] + c) * (3 * CC) + h * DD + ds * 32 + g * 8];

    f32x4 O[2][4];
#pragma unroll
    for (int q = 0; q < 2; q++)
#pragma unroll
        for (int nd = 0; nd < 4; nd++) O[q][nd] = fz;
    float mX[2] = {-1e30f, -1e30f}, lX[2] = {0.f, 0.f};

    u16* Psw = &Ps[w * 2048];

    // ---- prologue: stage tile 0 into buffer 0 ----
    {
        u16x8 vv[2];
#pragma unroll
        for (int r = 0; r < 2; r++) {
            int d0 = w * 8 + r * 32;
            vv[r] = *(const u16x8*)&QKV[(rowbase + l) * (3 * CC) + 2 * CC + h * DD + d0];
        }
#pragma unroll
        for (int r = 0; r < 2; r++) {
            int row = w * 8 + r * 32 + krow;
            const char* src = (const char*)(QKV + (rowbase + row) * (3 * CC) + CC + h * DD) + kcolb;
            gload_lds16(src, &Ks[r * 2048 + w * 512]);
        }
#pragma unroll
        for (int r = 0; r < 2; r++) {
            int d0 = w * 8 + r * 32;
#pragma unroll
            for (int ii = 0; ii < 8; ii++)
                Vs[(d0 + ii) * 64 + (l ^ (ii << 3))] = vv[r][ii];
        }
        asm volatile("s_waitcnt vmcnt(0)" ::: "memory");
        __syncthreads();
    }

    const int ntB = qtB + 1;  // staged kv tiles
    int cur = 0;
    for (int t = 0; t < ntB; t++) {
        const int kv0 = t * 64;
        const bool more = (t + 1 < ntB);
        const int kbase = cur * 4096;

        // ---- issue next tile's loads (overlap with compute) ----
        u16x8 vn[2];
        if (more) {
            const int nkv0 = kv0 + 64;
#pragma unroll
            for (int r = 0; r < 2; r++) {
                int row = w * 8 + r * 32 + krow;
                const char* src = (const char*)(QKV + (rowbase + nkv0 + row) * (3 * CC) + CC + h * DD) + kcolb;
                gload_lds16(src, &Ks[(kbase ^ 4096) + r * 2048 + w * 512]);
            }
#pragma unroll
            for (int r = 0; r < 2; r++) {
                int d0 = w * 8 + r * 32;
                vn[r] = *(const u16x8*)&QKV[(rowbase + nkv0 + l) * (3 * CC) + 2 * CC + h * DD + d0];
            }
        }

        // ---- compute ----
        const int thr[2] = {qrow0[0] + c - kv0, qrow0[1] + c - kv0};
        const bool nm[2] = {t == qtB, t == qtA};
        if (t <= qtA)
            tile_step<2>(&Ks[kbase], &Vs[kbase], Psw, qa, O, mX, lX, thr, nm, c, g);
        else
            tile_step<1>(&Ks[kbase], &Vs[kbase], Psw, qa, O, mX, lX, thr, nm, c, g);

        // ---- land next tile's V into other buffer ----
        if (more) {
#pragma unroll
            for (int r = 0; r < 2; r++) {
                int d0 = w * 8 + r * 32;
#pragma unroll
                for (int ii = 0; ii < 8; ii++)
                    Vs[(kbase ^ 4096) + (d0 + ii) * 64 + (l ^ (ii << 3))] = vn[r][ii];
            }
        }
        asm volatile("s_waitcnt vmcnt(0)" ::: "memory");
        __syncthreads();
        cur ^= 1;
    }

    // ---- epilogue: normalize, gate, write (O^T layout: lane has q=c, d=nd*16+g*4+j) ----
    float gv = gates[depth];
    float sg = 1.f / (1.f + __expf(-gv));
#pragma unroll
    for (int q = 0; q < 2; q++) {
        float invl = 1.f / lX[q];
        size_t base = (rowbase + qrow0[q] + c) * CC + h * DD;
#pragma unroll
        for (int nd = 0; nd < 4; nd++) {
            int d = nd * 16 + g * 4;
            f32x4 res;
#pragma unroll
            for (int j = 0; j < 4; j++) res[j] = O[q][nd][j] * invl;
            if (depth > 0) {
                f32x4 prev = *(const f32x4*)&attF[base + d];
#pragma unroll
                for (int j = 0; j < 4; j++) res[j] = sg * res[j] + (1.f - sg) * prev[j];
            }
            if (depth < 2) *(f32x4*)&attF[base + d] = res;
            u16x4 rb;
#pragma unroll
            for (int j = 0; j < 4; j++) rb[j] = f2bf(res[j]);
            *(u16x4*)&attB[base + d] = rb;
        }
    }
}

// ---------------- host ----------------
extern "C" void kernel_launch(void* const* d_in, const int* in_sizes, int n_in,
                              void* d_out, int out_size, void* d_ws, size_t ws_size,
                              hipStream_t stream) {
    const float* x      = (const float*)d_in[0];
    const float* W_attn = (const float*)d_in[1];
    const float* b_attn = (const float*)d_in[2];
    const float* W_proj = (const float*)d_in[3];
    const float* b_proj = (const float*)d_in[4];
    const float* gates  = (const float*)d_in[5];
    float* out = (float*)d_out;

    // ws layout (40 MiB):
    //   [0,8M)    Xb   [4096][1024] bf16  -- dead after QKV GEMM; reused as attB
    //   [8M,14M)  Wta  [3072][1024] bf16  (W_attn^T)
    //   [14M,16M) Wtp  [1024][1024] bf16  (W_proj^T)
    //   [16M,40M) QKV  [4096][3072] bf16
    // attF (fp32 gating state) aliases d_out (overwritten by final GEMM; never read-before-write).
    char* ws = (char*)d_ws;
    u16*   Xb   = (u16*)(ws);
    u16*   attB = (u16*)(ws);               // alias of Xb (Xb dead by then)
    u16*   Wta  = (u16*)(ws + 8388608);
    u16*   Wtp  = (u16*)(ws + 14680064);
    u16*   QKV  = (u16*)(ws + 16777216);
    float* attF = out;                      // alias of d_out
    (void)ws_size; (void)in_sizes; (void)n_in; (void)out_size;

    cvt_x<<<4096, 256, 0, stream>>>(x, Xb, 1048576);
    cvt_w_t<<<dim3(96, 32), 256, 0, stream>>>(W_attn, Wta, 1024, 3072);
    cvt_w_t<<<dim3(32, 32), 256, 0, stream>>>(W_proj, Wtp, 1024, 1024);

    // QKV projection: [4096,1024] x [1024,3072] -> bf16 [4096][3072]
    gemm_bf16<0><<<dim3(24, 32), 256, 0, stream>>>(Xb, Wta, b_attn, QKV, 1024, 3072);

    for (int depth = 0; depth < 3; depth++) {
        attn_kernel<<<dim3(16, 32), 256, 0, stream>>>(QKV, gates, attF, attB, depth);
        if (depth < 2) {
            // refinement: att_bf16 x W_attn[:, :2048]^T -> new q,k into QKV cols [0,2048)
            gemm_bf16<0><<<dim3(16, 32), 256, 0, stream>>>(attB, Wta, b_attn, QKV, 1024, 3072);
        }
    }
    // output projection -> fp32 d_out
    gemm_bf16<1><<<dim3(8, 32), 256, 0, stream>>>(attB, Wtp, b_proj, out, 1024, 1024);
}

// Round 8
// 381.054 us; speedup vs baseline: 1.2921x; 1.2921x over previous
//
#include <hip/hip_runtime.h>

typedef unsigned short u16;
typedef unsigned int u32;
typedef __bf16 bf16x8 __attribute__((ext_vector_type(8)));
typedef __bf16 bf16x2 __attribute__((ext_vector_type(2)));
typedef __bf16 bf16x4 __attribute__((ext_vector_type(4)));
typedef float f32x4 __attribute__((ext_vector_type(4)));
typedef u16 u16x8 __attribute__((ext_vector_type(8)));

#define DEV static __device__ __forceinline__

// B=2, T=2048, C=1024, H=16, D=64, DEPTH=3
#define TT 2048
#define CC 1024
#define HH 16
#define DD 64

DEV u16 f2bf(float f) {
    u32 u = __float_as_uint(f);
    u += 0x7fffu + ((u >> 16) & 1u);
    return (u16)(u >> 16);
}

DEV void gload_lds16(const void* g, void* l) {
    __builtin_amdgcn_global_load_lds(
        (const __attribute__((address_space(1))) void*)g,
        (__attribute__((address_space(3))) void*)l,
        16, 0, 0);
}

// ---------------- converts ----------------
__global__ __launch_bounds__(256) void cvt_x(const float* __restrict__ x,
                                             u16* __restrict__ xb, int n4) {
    int i = blockIdx.x * 256 + threadIdx.x;
    if (i < n4) {
        float4 v = ((const float4*)x)[i];
        u16 o0 = f2bf(v.x), o1 = f2bf(v.y), o2 = f2bf(v.z), o3 = f2bf(v.w);
        u32 lo = (u32)o0 | ((u32)o1 << 16);
        u32 hi = (u32)o2 | ((u32)o3 << 16);
        ((u32*)xb)[i * 2]     = lo;
        ((u32*)xb)[i * 2 + 1] = hi;
    }
}

// W [K][N] fp32 -> Wt [N][K] bf16
__global__ __launch_bounds__(256) void cvt_w_t(const float* __restrict__ W,
                                               u16* __restrict__ Wt, int K, int N) {
    __shared__ float tile[32][33];
    int n0 = blockIdx.x * 32, k0 = blockIdx.y * 32;
    int tx = threadIdx.x & 31, ty = threadIdx.x >> 5;  // 32 x 8
#pragma unroll
    for (int i = 0; i < 4; i++)
        tile[ty + i * 8][tx] = W[(size_t)(k0 + ty + i * 8) * N + n0 + tx];
    __syncthreads();
#pragma unroll
    for (int i = 0; i < 4; i++) {
        int rr = ty + i * 8;
        Wt[(size_t)(n0 + rr) * K + k0 + tx] = f2bf(tile[tx][rr]);
    }
}

// ---------------- GEMM: C[M,N] = A[M,K](bf16) * Bt[N,K]^T(bf16) + bias ----------------
// 128x128 tile, BK=32, 4 waves. T3-minimum 2-phase: double-buffered LDS,
// stage(t+1) issued BEFORE compute(t), single vmcnt(0)+barrier per K-step.
// (Measured R7: non-attn portion 188 -> 132 us vs the drain-per-step version.)
template <int OUTF>
__global__ __launch_bounds__(256) void gemm_bf16(const u16* __restrict__ A,
                                                 const u16* __restrict__ Bt,
                                                 const float* __restrict__ bias,
                                                 void* __restrict__ Cout,
                                                 int K, int ldc) {
    __shared__ __align__(16) u16 As[8192];  // 2 x [128][32]
    __shared__ __align__(16) u16 Bs[8192];

    const int tid = threadIdx.x;
    const int w = tid >> 6, l = tid & 63;
    const int wr = w >> 1, wc = w & 1;
    const int c = l & 15, g = l >> 4;
    const int rowB = blockIdx.y * 128;
    const int colB = blockIdx.x * 128;
    const int sr = l >> 2;          // staging row-in-quarter
    const int sk = (l & 3) * 8;     // staging k elem offset

    auto stage = [&](int t, int bb) {
#pragma unroll
        for (int i = 0; i < 2; i++) {
            int r = i * 64 + w * 16 + sr;
            gload_lds16(A + (size_t)(rowB + r) * K + t * 32 + sk, &As[bb * 4096 + i * 2048 + w * 512]);
            gload_lds16(Bt + (size_t)(colB + r) * K + t * 32 + sk, &Bs[bb * 4096 + i * 2048 + w * 512]);
        }
    };

    const f32x4 fz = {0.f, 0.f, 0.f, 0.f};
    f32x4 acc[4][4];
#pragma unroll
    for (int m = 0; m < 4; m++)
#pragma unroll
        for (int n = 0; n < 4; n++) acc[m][n] = fz;

    const int NT = K >> 5;
    stage(0, 0);
    asm volatile("s_waitcnt vmcnt(0)" ::: "memory");
    __syncthreads();

    int cur = 0;
    for (int t = 0; t < NT; t++) {
        if (t + 1 < NT) stage(t + 1, cur ^ 1);   // loads fly during compute
        const int kb = cur * 4096;
        bf16x8 af[4], bfr[4];
#pragma unroll
        for (int m = 0; m < 4; m++)
            af[m] = *(const bf16x8*)&As[kb + (wr * 64 + m * 16 + c) * 32 + g * 8];
#pragma unroll
        for (int n = 0; n < 4; n++)
            bfr[n] = *(const bf16x8*)&Bs[kb + (wc * 64 + n * 16 + c) * 32 + g * 8];
#pragma unroll
        for (int m = 0; m < 4; m++)
#pragma unroll
            for (int n = 0; n < 4; n++)
                acc[m][n] = __builtin_amdgcn_mfma_f32_16x16x32_bf16(af[m], bfr[n], acc[m][n], 0, 0, 0);
        asm volatile("s_waitcnt vmcnt(0)" ::: "memory");
        __syncthreads();  // next tile landed AND everyone done reading buf cur
        cur ^= 1;
    }

    const int orow = rowB + wr * 64;
    const int ocol = colB + wc * 64;
#pragma unroll
    for (int m = 0; m < 4; m++)
#pragma unroll
        for (int n = 0; n < 4; n++) {
            int col = ocol + n * 16 + c;
            float bv = bias[col];
#pragma unroll
            for (int j = 0; j < 4; j++) {
                int row = orow + m * 16 + g * 4 + j;
                float v = acc[m][n][j] + bv;
                if (OUTF)
                    ((float*)Cout)[(size_t)row * ldc + col] = v;
                else
                    ((u16*)Cout)[(size_t)row * ldc + col] = f2bf(v);
            }
        }
}

// ---------------- flash causal attention, one depth ----------------
// Swapped-operand scheme: S = mfma(K, Q) -> S[kv][q=c] lane-local per q-row;
// exp2-domain online softmax (scale folded: SCL = 0.125*log2e);
// P packed via compiler bf16 casts (no inline asm - m240); PV = mfma(V^T, P).
// Pair-balanced: block handles q-tiles (qp, 31-qp) sharing staged K/V tiles.
// Structure = Round-6-measured 66us version; NO setprio, NO defer-max.
template <int NQ>
DEV void tile_step(const u16* __restrict__ Kb, const u16* __restrict__ Vb,
                   u16* __restrict__ Psw, const bf16x8 (*qa)[2], f32x4 (*O)[4],
                   float* mX, float* lX, const int* thr, const bool* nm,
                   int c, int g) {
    const f32x4 fz = {0.f, 0.f, 0.f, 0.f};
    const int swz = (c & 7) << 3;
    const float SCL = 0.18033688011112042f;  // 0.125 * log2(e)
    f32x4 s[NQ][4];
#pragma unroll
    for (int q = 0; q < NQ; q++)
#pragma unroll
        for (int m = 0; m < 4; m++) s[q][m] = fz;
    // S = K Q^T  (C layout: row=kv, col=q=c)
#pragma unroll
    for (int ds = 0; ds < 2; ds++)
#pragma unroll
        for (int m = 0; m < 4; m++) {
            bf16x8 kb = *(const bf16x8*)&Kb[(m * 16 + c) * 64 + ((ds * 32 + g * 8) ^ swz)];
#pragma unroll
            for (int q = 0; q < NQ; q++)
                s[q][m] = __builtin_amdgcn_mfma_f32_16x16x32_bf16(kb, qa[q][ds], s[q][m], 0, 0, 0);
        }
#pragma unroll
    for (int q = 0; q < NQ; q++) {
        float m0 = -1e30f;
        if (nm[q]) {
#pragma unroll
            for (int m = 0; m < 4; m++)
#pragma unroll
                for (int j = 0; j < 4; j++) {
                    int kvr = m * 16 + g * 4 + j;
                    float v = (kvr <= thr[q]) ? s[q][m][j] * SCL : -1e30f;
                    s[q][m][j] = v;
                    m0 = fmaxf(m0, v);
                }
        } else {
#pragma unroll
            for (int m = 0; m < 4; m++)
#pragma unroll
                for (int j = 0; j < 4; j++) {
                    float v = s[q][m][j] * SCL;
                    s[q][m][j] = v;
                    m0 = fmaxf(m0, v);
                }
        }
        m0 = fmaxf(m0, __shfl_xor(m0, 16, 64));
        m0 = fmaxf(m0, __shfl_xor(m0, 32, 64));
        float mn = fmaxf(mX[q], m0);
        float esc = exp2f(mX[q] - mn);
        mX[q] = mn;
        float rsum = 0.f;
#pragma unroll
        for (int m = 0; m < 4; m++)
#pragma unroll
            for (int j = 0; j < 4; j++) {
                float p = exp2f(s[q][m][j] - mn);
                s[q][m][j] = p;
                rsum += p;
            }
        rsum += __shfl_xor(rsum, 16, 64);
        rsum += __shfl_xor(rsum, 32, 64);
        lX[q] = lX[q] * esc + rsum;
#pragma unroll
        for (int nd = 0; nd < 4; nd++)
#pragma unroll
            for (int j = 0; j < 4; j++) O[q][nd][j] *= esc;
        // P write: Ps[q=c][kv], pairs via compiler bf16 casts (emits cvt_pk)
#pragma unroll
        for (int m = 0; m < 4; m++)
#pragma unroll
            for (int jj = 0; jj < 2; jj++) {
                bf16x2 pw = {(__bf16)s[q][m][jj * 2], (__bf16)s[q][m][jj * 2 + 1]};
                int kvi = (m * 16 + g * 4 + jj * 2) ^ swz;
                *(bf16x2*)&Psw[q * 1024 + c * 64 + kvi] = pw;
            }
    }
    asm volatile("s_waitcnt lgkmcnt(0)" ::: "memory");
    __builtin_amdgcn_sched_barrier(0);
    // O += V^T P^T  (C layout: row=d, col=q=c)
#pragma unroll
    for (int ks = 0; ks < 2; ks++) {
        bf16x8 pa[NQ];
#pragma unroll
        for (int q = 0; q < NQ; q++)
            pa[q] = *(const bf16x8*)&Psw[q * 1024 + c * 64 + ((ks * 32 + g * 8) ^ swz)];
#pragma unroll
        for (int nd = 0; nd < 4; nd++) {
            bf16x8 vb = *(const bf16x8*)&Vb[(nd * 16 + c) * 64 + ((ks * 32 + g * 8) ^ swz)];
#pragma unroll
            for (int q = 0; q < NQ; q++)
                O[q][nd] = __builtin_amdgcn_mfma_f32_16x16x32_bf16(vb, pa[q], O[q][nd], 0, 0, 0);
        }
    }
}

__global__ __launch_bounds__(256) void attn_kernel(const u16* __restrict__ QKV,  // [B*T][3C]
                                                   const float* __restrict__ gates,
                                                   float* __restrict__ attF,  // [B*T][C] fp32 state (= d_out)
                                                   u16* __restrict__ attB,    // [B*T][C] bf16 copy
                                                   int depth) {
    __shared__ __align__(16) u16 Ks[8192];  // 2 x 8KB
    __shared__ __align__(16) u16 Vs[8192];  // 2 x 8KB
    __shared__ __align__(16) u16 Ps[8192];  // 4 waves x 2 qsets x 2KB

    const int tid = threadIdx.x;
    const int w = tid >> 6, l = tid & 63;
    const int c = l & 15, g = l >> 4;

    // XCD-aware bijective remap: 512 blocks, each XCD owns 4 bh values
    const int f = blockIdx.y * 16 + blockIdx.x;
    const int xcd = f & 7;
    const int idx = f >> 3;                 // 0..63
    const int bh = xcd + 8 * (idx & 3);     // 0..31
    const int qp = idx >> 2;                // pair 0..15
    const int b = bh >> 4, h = bh & 15;
    const int qtB = 31 - qp;                // qset0 (always active)
    const int qtA = qp;                     // qset1 (active t <= qtA)
    const size_t rowbase = (size_t)b * TT;
    const int qrow0[2] = {qtB * 64 + w * 16, qtA * 64 + w * 16};
    const f32x4 fz = {0.f, 0.f, 0.f, 0.f};

    // staging constants
    const int krow = l >> 3;
    const int kcolb = (((l & 7) ^ krow) << 4);

    // Q fragments (B-operand layout): lane holds Q[q=qrow0+c][k=ds*32+g*8..]
    bf16x8 qa[2][2];
#pragma unroll
    for (int q = 0; q < 2; q++)
#pragma unroll
        for (int ds = 0; ds < 2; ds++)
            qa[q][ds] = *(const bf16x8*)&QKV[(rowbase + qrow0[q] + c) * (3 * CC) + h * DD + ds * 32 + g * 8];

    f32x4 O[2][4];
#pragma unroll
    for (int q = 0; q < 2; q++)
#pragma unroll
        for (int nd = 0; nd < 4; nd++) O[q][nd] = fz;
    float mX[2] = {-1e30f, -1e30f}, lX[2] = {0.f, 0.f};

    u16* Psw = &Ps[w * 2048];

    // ---- prologue: stage tile 0 into buffer 0 ----
    {
        u16x8 vv[2];
#pragma unroll
        for (int r = 0; r < 2; r++) {
            int d0 = w * 8 + r * 32;
            vv[r] = *(const u16x8*)&QKV[(rowbase + l) * (3 * CC) + 2 * CC + h * DD + d0];
        }
#pragma unroll
        for (int r = 0; r < 2; r++) {
            int row = w * 8 + r * 32 + krow;
            const char* src = (const char*)(QKV + (rowbase + row) * (3 * CC) + CC + h * DD) + kcolb;
            gload_lds16(src, &Ks[r * 2048 + w * 512]);
        }
#pragma unroll
        for (int r = 0; r < 2; r++) {
            int d0 = w * 8 + r * 32;
#pragma unroll
            for (int ii = 0; ii < 8; ii++)
                Vs[(d0 + ii) * 64 + (l ^ (ii << 3))] = vv[r][ii];
        }
        asm volatile("s_waitcnt vmcnt(0)" ::: "memory");
        __syncthreads();
    }

    const int ntB = qtB + 1;  // staged kv tiles
    int cur = 0;
    for (int t = 0; t < ntB; t++) {
        const int kv0 = t * 64;
        const bool more = (t + 1 < ntB);
        const int kbase = cur * 4096;

        // ---- issue next tile's loads (overlap with compute) ----
        u16x8 vn[2];
        if (more) {
            const int nkv0 = kv0 + 64;
#pragma unroll
            for (int r = 0; r < 2; r++) {
                int row = w * 8 + r * 32 + krow;
                const char* src = (const char*)(QKV + (rowbase + nkv0 + row) * (3 * CC) + CC + h * DD) + kcolb;
                gload_lds16(src, &Ks[(kbase ^ 4096) + r * 2048 + w * 512]);
            }
#pragma unroll
            for (int r = 0; r < 2; r++) {
                int d0 = w * 8 + r * 32;
                vn[r] = *(const u16x8*)&QKV[(rowbase + nkv0 + l) * (3 * CC) + 2 * CC + h * DD + d0];
            }
        }

        // ---- compute ----
        const int thr[2] = {qrow0[0] + c - kv0, qrow0[1] + c - kv0};
        const bool nm[2] = {t == qtB, t == qtA};
        if (t <= qtA)
            tile_step<2>(&Ks[kbase], &Vs[kbase], Psw, qa, O, mX, lX, thr, nm, c, g);
        else
            tile_step<1>(&Ks[kbase], &Vs[kbase], Psw, qa, O, mX, lX, thr, nm, c, g);

        // ---- land next tile's V into other buffer ----
        if (more) {
#pragma unroll
            for (int r = 0; r < 2; r++) {
                int d0 = w * 8 + r * 32;
#pragma unroll
                for (int ii = 0; ii < 8; ii++)
                    Vs[(kbase ^ 4096) + (d0 + ii) * 64 + (l ^ (ii << 3))] = vn[r][ii];
            }
        }
        asm volatile("s_waitcnt vmcnt(0)" ::: "memory");
        __syncthreads();
        cur ^= 1;
    }

    // ---- epilogue: normalize, gate, write (O^T layout: lane has q=c, d=nd*16+g*4+j) ----
    float gv = gates[depth];
    float sg = 1.f / (1.f + __expf(-gv));
#pragma unroll
    for (int q = 0; q < 2; q++) {
        float invl = 1.f / lX[q];
        size_t base = (rowbase + qrow0[q] + c) * CC + h * DD;
#pragma unroll
        for (int nd = 0; nd < 4; nd++) {
            int d = nd * 16 + g * 4;
            f32x4 res;
#pragma unroll
            for (int j = 0; j < 4; j++) res[j] = O[q][nd][j] * invl;
            if (depth > 0) {
                f32x4 prev = *(const f32x4*)&attF[base + d];
#pragma unroll
                for (int j = 0; j < 4; j++) res[j] = sg * res[j] + (1.f - sg) * prev[j];
            }
            if (depth < 2) *(f32x4*)&attF[base + d] = res;
            bf16x4 rb = {(__bf16)res[0], (__bf16)res[1], (__bf16)res[2], (__bf16)res[3]};
            *(bf16x4*)&attB[base + d] = rb;
        }
    }
}

// ---------------- host ----------------
extern "C" void kernel_launch(void* const* d_in, const int* in_sizes, int n_in,
                              void* d_out, int out_size, void* d_ws, size_t ws_size,
                              hipStream_t stream) {
    const float* x      = (const float*)d_in[0];
    const float* W_attn = (const float*)d_in[1];
    const float* b_attn = (const float*)d_in[2];
    const float* W_proj = (const float*)d_in[3];
    const float* b_proj = (const float*)d_in[4];
    const float* gates  = (const float*)d_in[5];
    float* out = (float*)d_out;

    // ws layout (40 MiB):
    //   [0,8M)    Xb   [4096][1024] bf16  -- dead after QKV GEMM; reused as attB
    //   [8M,14M)  Wta  [3072][1024] bf16  (W_attn^T)
    //   [14M,16M) Wtp  [1024][1024] bf16  (W_proj^T)
    //   [16M,40M) QKV  [4096][3072] bf16
    // attF (fp32 gating state) aliases d_out (overwritten by final GEMM; never read-before-write).
    char* ws = (char*)d_ws;
    u16*   Xb   = (u16*)(ws);
    u16*   attB = (u16*)(ws);               // alias of Xb (Xb dead by then)
    u16*   Wta  = (u16*)(ws + 8388608);
    u16*   Wtp  = (u16*)(ws + 14680064);
    u16*   QKV  = (u16*)(ws + 16777216);
    float* attF = out;                      // alias of d_out
    (void)ws_size; (void)in_sizes; (void)n_in; (void)out_size;

    cvt_x<<<4096, 256, 0, stream>>>(x, Xb, 1048576);
    cvt_w_t<<<dim3(96, 32), 256, 0, stream>>>(W_attn, Wta, 1024, 3072);
    cvt_w_t<<<dim3(32, 32), 256, 0, stream>>>(W_proj, Wtp, 1024, 1024);

    // QKV projection: [4096,1024] x [1024,3072] -> bf16 [4096][3072]
    gemm_bf16<0><<<dim3(24, 32), 256, 0, stream>>>(Xb, Wta, b_attn, QKV, 1024, 3072);

    for (int depth = 0; depth < 3; depth++) {
        attn_kernel<<<dim3(16, 32), 256, 0, stream>>>(QKV, gates, attF, attB, depth);
        if (depth < 2) {
            // refinement: att_bf16 x W_attn[:, :2048]^T -> new q,k into QKV cols [0,2048)
            gemm_bf16<0><<<dim3(16, 32), 256, 0, stream>>>(attB, Wta, b_attn, QKV, 1024, 3072);
        }
    }
    // output projection -> fp32 d_out
    gemm_bf16<1><<<dim3(8, 32), 256, 0, stream>>>(attB, Wtp, b_proj, out, 1024, 1024);
}

// Round 9
// 355.390 us; speedup vs baseline: 1.3854x; 1.0722x over previous
//
#include <hip/hip_runtime.h>

typedef unsigned short u16;
typedef unsigned int u32;
typedef __bf16 bf16x8 __attribute__((ext_vector_type(8)));
typedef __bf16 bf16x2 __attribute__((ext_vector_type(2)));
typedef __bf16 bf16x4 __attribute__((ext_vector_type(4)));
typedef float f32x4 __attribute__((ext_vector_type(4)));
typedef u16 u16x8 __attribute__((ext_vector_type(8)));

#define DEV static __device__ __forceinline__

// B=2, T=2048, C=1024, H=16, D=64, DEPTH=3
#define TT 2048
#define CC 1024
#define HH 16
#define DD 64

DEV u16 f2bf(float f) {
    u32 u = __float_as_uint(f);
    u += 0x7fffu + ((u >> 16) & 1u);
    return (u16)(u >> 16);
}

DEV void gload_lds16(const void* g, void* l) {
    __builtin_amdgcn_global_load_lds(
        (const __attribute__((address_space(1))) void*)g,
        (__attribute__((address_space(3))) void*)l,
        16, 0, 0);
}

// ---------------- converts ----------------
__global__ __launch_bounds__(256) void cvt_x(const float* __restrict__ x,
                                             u16* __restrict__ xb, int n4) {
    int i = blockIdx.x * 256 + threadIdx.x;
    if (i < n4) {
        float4 v = ((const float4*)x)[i];
        u16 o0 = f2bf(v.x), o1 = f2bf(v.y), o2 = f2bf(v.z), o3 = f2bf(v.w);
        u32 lo = (u32)o0 | ((u32)o1 << 16);
        u32 hi = (u32)o2 | ((u32)o3 << 16);
        ((u32*)xb)[i * 2]     = lo;
        ((u32*)xb)[i * 2 + 1] = hi;
    }
}

// W [K][N] fp32 -> Wt [N][K] bf16
__global__ __launch_bounds__(256) void cvt_w_t(const float* __restrict__ W,
                                               u16* __restrict__ Wt, int K, int N) {
    __shared__ float tile[32][33];
    int n0 = blockIdx.x * 32, k0 = blockIdx.y * 32;
    int tx = threadIdx.x & 31, ty = threadIdx.x >> 5;  // 32 x 8
#pragma unroll
    for (int i = 0; i < 4; i++)
        tile[ty + i * 8][tx] = W[(size_t)(k0 + ty + i * 8) * N + n0 + tx];
    __syncthreads();
#pragma unroll
    for (int i = 0; i < 4; i++) {
        int rr = ty + i * 8;
        Wt[(size_t)(n0 + rr) * K + k0 + tx] = f2bf(tile[tx][rr]);
    }
}

// ---------------- GEMM: C[M,N] = A[M,K](bf16) * Bt[N,K]^T(bf16) + bias ----------------
// 128x128 tile, BK=32, 4 waves. T3-minimum 2-phase: double-buffered LDS,
// stage(t+1) issued BEFORE compute(t), single vmcnt(0)+barrier per K-step.
template <int OUTF>
__global__ __launch_bounds__(256) void gemm_bf16(const u16* __restrict__ A,
                                                 const u16* __restrict__ Bt,
                                                 const float* __restrict__ bias,
                                                 void* __restrict__ Cout,
                                                 int K, int ldc) {
    __shared__ __align__(16) u16 As[8192];  // 2 x [128][32]
    __shared__ __align__(16) u16 Bs[8192];

    const int tid = threadIdx.x;
    const int w = tid >> 6, l = tid & 63;
    const int wr = w >> 1, wc = w & 1;
    const int c = l & 15, g = l >> 4;
    const int rowB = blockIdx.y * 128;
    const int colB = blockIdx.x * 128;
    const int sr = l >> 2;          // staging row-in-quarter
    const int sk = (l & 3) * 8;     // staging k elem offset

    auto stage = [&](int t, int bb) {
#pragma unroll
        for (int i = 0; i < 2; i++) {
            int r = i * 64 + w * 16 + sr;
            gload_lds16(A + (size_t)(rowB + r) * K + t * 32 + sk, &As[bb * 4096 + i * 2048 + w * 512]);
            gload_lds16(Bt + (size_t)(colB + r) * K + t * 32 + sk, &Bs[bb * 4096 + i * 2048 + w * 512]);
        }
    };

    const f32x4 fz = {0.f, 0.f, 0.f, 0.f};
    f32x4 acc[4][4];
#pragma unroll
    for (int m = 0; m < 4; m++)
#pragma unroll
        for (int n = 0; n < 4; n++) acc[m][n] = fz;

    const int NT = K >> 5;
    stage(0, 0);
    asm volatile("s_waitcnt vmcnt(0)" ::: "memory");
    __syncthreads();

    int cur = 0;
    for (int t = 0; t < NT; t++) {
        if (t + 1 < NT) stage(t + 1, cur ^ 1);   // loads fly during compute
        const int kb = cur * 4096;
        bf16x8 af[4], bfr[4];
#pragma unroll
        for (int m = 0; m < 4; m++)
            af[m] = *(const bf16x8*)&As[kb + (wr * 64 + m * 16 + c) * 32 + g * 8];
#pragma unroll
        for (int n = 0; n < 4; n++)
            bfr[n] = *(const bf16x8*)&Bs[kb + (wc * 64 + n * 16 + c) * 32 + g * 8];
#pragma unroll
        for (int m = 0; m < 4; m++)
#pragma unroll
            for (int n = 0; n < 4; n++)
                acc[m][n] = __builtin_amdgcn_mfma_f32_16x16x32_bf16(af[m], bfr[n], acc[m][n], 0, 0, 0);
        asm volatile("s_waitcnt vmcnt(0)" ::: "memory");
        __syncthreads();  // next tile landed AND everyone done reading buf cur
        cur ^= 1;
    }

    const int orow = rowB + wr * 64;
    const int ocol = colB + wc * 64;
#pragma unroll
    for (int m = 0; m < 4; m++)
#pragma unroll
        for (int n = 0; n < 4; n++) {
            int col = ocol + n * 16 + c;
            float bv = bias[col];
#pragma unroll
            for (int j = 0; j < 4; j++) {
                int row = orow + m * 16 + g * 4 + j;
                float v = acc[m][n][j] + bv;
                if (OUTF)
                    ((float*)Cout)[(size_t)row * ldc + col] = v;
                else
                    ((u16*)Cout)[(size_t)row * ldc + col] = f2bf(v);
            }
        }
}

// ---------------- flash causal attention, one depth ----------------
// 8-wave (512-thread) pair blocks: waves 0-3 own q-tile qtB, waves 4-7 own qtA,
// all sharing staged K/V tiles (16 waves/CU vs 8 before -> exp/MFMA pipe overlap).
// Swapped-operand: S = mfma(K, Q) -> S[kv][q=c] lane-local; exp2-domain softmax
// via fmaf(s,SCL,-mn); P via compiler bf16 casts; PV = mfma(V^T, P) -> O^T[d][q=c].
DEV void tile_step(const u16* __restrict__ Kb, const u16* __restrict__ Vb,
                   u16* __restrict__ Psw, const bf16x8* qa, f32x4* O,
                   float& mX, float& lX, int thr, bool nm, int c, int g) {
    const f32x4 fz = {0.f, 0.f, 0.f, 0.f};
    const int swz = (c & 7) << 3;
    const float SCL = 0.18033688011112042f;  // 0.125 * log2(e)
    f32x4 s[4];
#pragma unroll
    for (int m = 0; m < 4; m++) s[m] = fz;
    // S = K Q^T  (C layout: row=kv, col=q=c)
#pragma unroll
    for (int ds = 0; ds < 2; ds++)
#pragma unroll
        for (int m = 0; m < 4; m++) {
            bf16x8 kb = *(const bf16x8*)&Kb[(m * 16 + c) * 64 + ((ds * 32 + g * 8) ^ swz)];
            s[m] = __builtin_amdgcn_mfma_f32_16x16x32_bf16(kb, qa[ds], s[m], 0, 0, 0);
        }
    // raw-domain max (max commutes with positive scale); mask -> -1e30
    float m0 = -1e30f;
    if (nm) {
#pragma unroll
        for (int m = 0; m < 4; m++)
#pragma unroll
            for (int j = 0; j < 4; j++) {
                int kvr = m * 16 + g * 4 + j;
                float v = (kvr <= thr) ? s[m][j] : -1e30f;
                s[m][j] = v;
                m0 = fmaxf(m0, v);
            }
    } else {
#pragma unroll
        for (int m = 0; m < 4; m++)
#pragma unroll
            for (int j = 0; j < 4; j++) m0 = fmaxf(m0, s[m][j]);
    }
    m0 = fmaxf(m0, __shfl_xor(m0, 16, 64));
    m0 = fmaxf(m0, __shfl_xor(m0, 32, 64));
    float mn = fmaxf(mX, m0 * SCL);
    float esc = exp2f(mX - mn);
    mX = mn;
    float rsum = 0.f;
#pragma unroll
    for (int m = 0; m < 4; m++)
#pragma unroll
        for (int j = 0; j < 4; j++) {
            float p = exp2f(fmaf(s[m][j], SCL, -mn));  // masked: -1e30*SCL-mn -> 0
            s[m][j] = p;
            rsum += p;
        }
    rsum += __shfl_xor(rsum, 16, 64);
    rsum += __shfl_xor(rsum, 32, 64);
    lX = lX * esc + rsum;
#pragma unroll
    for (int nd = 0; nd < 4; nd++)
#pragma unroll
        for (int j = 0; j < 4; j++) O[nd][j] *= esc;
    // P write: Ps[q=c][kv], pairs via compiler bf16 casts (emits cvt_pk)
#pragma unroll
    for (int m = 0; m < 4; m++)
#pragma unroll
        for (int jj = 0; jj < 2; jj++) {
            bf16x2 pw = {(__bf16)s[m][jj * 2], (__bf16)s[m][jj * 2 + 1]};
            int kvi = (m * 16 + g * 4 + jj * 2) ^ swz;
            *(bf16x2*)&Psw[c * 64 + kvi] = pw;
        }
    asm volatile("s_waitcnt lgkmcnt(0)" ::: "memory");
    __builtin_amdgcn_sched_barrier(0);
    // O += V^T P^T  (C layout: row=d, col=q=c)
#pragma unroll
    for (int ks = 0; ks < 2; ks++) {
        bf16x8 pa = *(const bf16x8*)&Psw[c * 64 + ((ks * 32 + g * 8) ^ swz)];
#pragma unroll
        for (int nd = 0; nd < 4; nd++) {
            bf16x8 vb = *(const bf16x8*)&Vb[(nd * 16 + c) * 64 + ((ks * 32 + g * 8) ^ swz)];
            O[nd] = __builtin_amdgcn_mfma_f32_16x16x32_bf16(vb, pa, O[nd], 0, 0, 0);
        }
    }
}

__global__ __launch_bounds__(512) void attn_kernel(const u16* __restrict__ QKV,  // [B*T][3C]
                                                   const float* __restrict__ gates,
                                                   float* __restrict__ attF,  // [B*T][C] fp32 state (= d_out)
                                                   u16* __restrict__ attB,    // [B*T][C] bf16 copy
                                                   int depth) {
    __shared__ __align__(16) u16 Ks[8192];  // 2 x 8KB dbuf
    __shared__ __align__(16) u16 Vs[8192];  // 2 x 8KB dbuf (V^T)
    __shared__ __align__(16) u16 Ps[8192];  // 8 waves x 2KB

    const int tid = threadIdx.x;
    const int w = tid >> 6, l = tid & 63;   // w in 0..7
    const int c = l & 15, g = l >> 4;

    // XCD-aware bijective remap: 512 blocks, each XCD owns 4 bh values
    const int f = blockIdx.y * 16 + blockIdx.x;
    const int xcd = f & 7;
    const int idx = f >> 3;                 // 0..63
    const int bh = xcd + 8 * (idx & 3);     // 0..31
    const int qp = idx >> 2;                // pair 0..15
    const int b = bh >> 4, h = bh & 15;
    const int qtB = 31 - qp;                // waves 0-3 (active all tiles)
    const int qtA = qp;                     // waves 4-7 (active t <= qtA)
    const int qset = w >> 2, wl = w & 3;
    const int qt = qset ? qtA : qtB;
    const size_t rowbase = (size_t)b * TT;
    const int qrow0 = qt * 64 + wl * 16;    // wave's 16 q rows
    const f32x4 fz = {0.f, 0.f, 0.f, 0.f};

    // staging constants: wave w covers K rows / V d-cols [w*8, w*8+8)
    const int krow = l >> 3;
    const int kcolb = (((l & 7) ^ krow) << 4);   // pre-swizzled byte col
    const int d0 = w * 8;

    // Q fragments (B-operand layout): lane holds Q[q=qrow0+c][k=ds*32+g*8..]
    bf16x8 qa[2];
#pragma unroll
    for (int ds = 0; ds < 2; ds++)
        qa[ds] = *(const bf16x8*)&QKV[(rowbase + qrow0 + c) * (3 * CC) + h * DD + ds * 32 + g * 8];

    f32x4 O[4];
#pragma unroll
    for (int nd = 0; nd < 4; nd++) O[nd] = fz;
    float mX = -1e30f, lX = 0.f;

    u16* Psw = &Ps[w * 1024];

    // ---- prologue: stage tile 0 into buffer 0 ----
    {
        u16x8 vv = *(const u16x8*)&QKV[(rowbase + l) * (3 * CC) + 2 * CC + h * DD + d0];
        const char* src = (const char*)(QKV + (rowbase + d0 + krow) * (3 * CC) + CC + h * DD) + kcolb;
        gload_lds16(src, &Ks[w * 512]);
#pragma unroll
        for (int ii = 0; ii < 8; ii++)
            Vs[(d0 + ii) * 64 + (l ^ (ii << 3))] = vv[ii];
        asm volatile("s_waitcnt vmcnt(0)" ::: "memory");
        __syncthreads();
    }

    const int ntB = qtB + 1;  // staged kv tiles
    int cur = 0;
    for (int t = 0; t < ntB; t++) {
        const int kv0 = t * 64;
        const bool more = (t + 1 < ntB);
        const int kbase = cur * 4096;

        // ---- issue next tile's loads (overlap with compute) ----
        u16x8 vn;
        if (more) {
            const int nkv0 = kv0 + 64;
            const char* src = (const char*)(QKV + (rowbase + nkv0 + d0 + krow) * (3 * CC) + CC + h * DD) + kcolb;
            gload_lds16(src, &Ks[(kbase ^ 4096) + w * 512]);
            vn = *(const u16x8*)&QKV[(rowbase + nkv0 + l) * (3 * CC) + 2 * CC + h * DD + d0];
        }

        // ---- compute (wave-uniform skip for qtA waves past their range) ----
        if (t <= qt)
            tile_step(&Ks[kbase], &Vs[kbase], Psw, qa, O, mX, lX,
                      qrow0 + c - kv0, t == qt, c, g);

        // ---- land next tile's V into other buffer ----
        if (more) {
#pragma unroll
            for (int ii = 0; ii < 8; ii++)
                Vs[(kbase ^ 4096) + (d0 + ii) * 64 + (l ^ (ii << 3))] = vn[ii];
        }
        asm volatile("s_waitcnt vmcnt(0)" ::: "memory");
        __syncthreads();
        cur ^= 1;
    }

    // ---- epilogue: normalize, gate, write (O^T layout: lane has q=c, d=nd*16+g*4+j) ----
    float gv = gates[depth];
    float sg = 1.f / (1.f + __expf(-gv));
    float invl = 1.f / lX;
    size_t base = (rowbase + qrow0 + c) * CC + h * DD;
#pragma unroll
    for (int nd = 0; nd < 4; nd++) {
        int d = nd * 16 + g * 4;
        f32x4 res;
#pragma unroll
        for (int j = 0; j < 4; j++) res[j] = O[nd][j] * invl;
        if (depth > 0) {
            f32x4 prev = *(const f32x4*)&attF[base + d];
#pragma unroll
            for (int j = 0; j < 4; j++) res[j] = sg * res[j] + (1.f - sg) * prev[j];
        }
        if (depth < 2) *(f32x4*)&attF[base + d] = res;
        bf16x4 rb = {(__bf16)res[0], (__bf16)res[1], (__bf16)res[2], (__bf16)res[3]};
        *(bf16x4*)&attB[base + d] = rb;
    }
}

// ---------------- host ----------------
extern "C" void kernel_launch(void* const* d_in, const int* in_sizes, int n_in,
                              void* d_out, int out_size, void* d_ws, size_t ws_size,
                              hipStream_t stream) {
    const float* x      = (const float*)d_in[0];
    const float* W_attn = (const float*)d_in[1];
    const float* b_attn = (const float*)d_in[2];
    const float* W_proj = (const float*)d_in[3];
    const float* b_proj = (const float*)d_in[4];
    const float* gates  = (const float*)d_in[5];
    float* out = (float*)d_out;

    // ws layout (40 MiB):
    //   [0,8M)    Xb   [4096][1024] bf16  -- dead after QKV GEMM; reused as attB
    //   [8M,14M)  Wta  [3072][1024] bf16  (W_attn^T)
    //   [14M,16M) Wtp  [1024][1024] bf16  (W_proj^T)
    //   [16M,40M) QKV  [4096][3072] bf16
    // attF (fp32 gating state) aliases d_out (overwritten by final GEMM; never read-before-write).
    char* ws = (char*)d_ws;
    u16*   Xb   = (u16*)(ws);
    u16*   attB = (u16*)(ws);               // alias of Xb (Xb dead by then)
    u16*   Wta  = (u16*)(ws + 8388608);
    u16*   Wtp  = (u16*)(ws + 14680064);
    u16*   QKV  = (u16*)(ws + 16777216);
    float* attF = out;                      // alias of d_out
    (void)ws_size; (void)in_sizes; (void)n_in; (void)out_size;

    cvt_x<<<4096, 256, 0, stream>>>(x, Xb, 1048576);
    cvt_w_t<<<dim3(96, 32), 256, 0, stream>>>(W_attn, Wta, 1024, 3072);
    cvt_w_t<<<dim3(32, 32), 256, 0, stream>>>(W_proj, Wtp, 1024, 1024);

    // QKV projection: [4096,1024] x [1024,3072] -> bf16 [4096][3072]
    gemm_bf16<0><<<dim3(24, 32), 256, 0, stream>>>(Xb, Wta, b_attn, QKV, 1024, 3072);

    for (int depth = 0; depth < 3; depth++) {
        attn_kernel<<<dim3(16, 32), 512, 0, stream>>>(QKV, gates, attF, attB, depth);
        if (depth < 2) {
            // refinement: att_bf16 x W_attn[:, :2048]^T -> new q,k into QKV cols [0,2048)
            gemm_bf16<0><<<dim3(16, 32), 256, 0, stream>>>(attB, Wta, b_attn, QKV, 1024, 3072);
        }
    }
    // output projection -> fp32 d_out
    gemm_bf16<1><<<dim3(8, 32), 256, 0, stream>>>(attB, Wtp, b_proj, out, 1024, 1024);
}